// Round 8
// baseline (353.021 us; speedup 1.0000x reference)
//
#include <hip/hip_runtime.h>
#include <stdint.h>

typedef unsigned int u32;
typedef unsigned long long u64;
typedef unsigned short u16;

// key = ((b*512 + z/2)*512 + y/2)*512 + x/2  in [0, 2^29)
// rec = (key<<3)|off. coarse = rec>>24 (8b), fine = (rec>>17)&127 (7b),
// bucket = key>>14 = rec>>17 (15b), local key = key & 0x3FFF (14b).
#define LBITS  14
#define LMASK  ((1u << LBITS) - 1u)
#define NBUCK  (1u << (29 - LBITS))      // 32768 fine buckets
#define BWORDS (1u << (LBITS - 5))       // 512 u32 bitmap words / bucket
#define WPL    (BWORDS / 64)             // 8 words per lane
#define WOPAD  (BWORDS + BWORDS / 32)    // padded word-offset array (bank-conflict fix)
#define FCAP   320                       // LDS feats slots per bucket
#define BPB    4                         // buckets (waves) per 256-thr block
#define NBLK2  (NBUCK / BPB)             // fused-pass blocks = 8192
#define TILE_A 8192                      // phase_a / part1 tile
#define SCAN_ELEM 2048                   // hierarchical scan: elems per block

#define ST_AGG (1ull << 62)
#define ST_PRE (2ull << 62)
#define ST_MSK (3ull << 62)

__device__ __forceinline__ u32 woidx(u32 w) { return w + (w >> 5); }

__device__ __forceinline__ u32 make_key(int4 c) {
    return ((((u32)c.x * 512u + ((u32)c.w >> 1)) * 512u + ((u32)c.z >> 1)) * 512u)
           + ((u32)c.y >> 1);
}

__global__ void fill_u32(u32* p, u32 v, u32 n) {
    u32 i = blockIdx.x * blockDim.x + threadIdx.x;
    if (i < n) p[i] = v;
}

// ---- phase A: coords -> linrec + per-tile coarse histogram (bin-major matrix)
__global__ void phase_a(const int4* __restrict__ coords, u32* __restrict__ linrec,
                        u32* __restrict__ histmat, int n, u32 NT) {
    __shared__ u32 h[256];
    int t = threadIdx.x;
    h[t] = 0; __syncthreads();
    u32 base = blockIdx.x * TILE_A;
    u32 m = min((u32)TILE_A, (u32)n - base);
    for (u32 j = t; j < m; j += 256u) {
        int4 c = coords[base + j];
        u32 key = make_key(c);
        u32 off = ((u32)c.y & 1u) | (((u32)c.z & 1u) << 1) | (((u32)c.w & 1u) << 2);
        u32 rec = (key << 3) | off;
        linrec[base + j] = rec;
        atomicAdd(&h[rec >> 24], 1u);
    }
    __syncthreads();
    histmat[(u32)t * NT + blockIdx.x] = h[t];   // bin-major: scan order = radix order
}

// ---- hierarchical exclusive scan: reduce -> small scan -> apply ----
__global__ void scan_reduce(const u32* __restrict__ data, u32* __restrict__ partial, u32 G) {
    __shared__ u32 s[256];
    u32 t = threadIdx.x;
    u32 base = blockIdx.x * SCAN_ELEM + t * 8u;
    u32 sum = 0;
    #pragma unroll
    for (int j = 0; j < 8; ++j) { u32 idx = base + j; if (idx < G) sum += data[idx]; }
    s[t] = sum; __syncthreads();
    for (int d = 128; d > 0; d >>= 1) { if ((int)t < d) s[t] += s[t + d]; __syncthreads(); }
    if (t == 0) partial[blockIdx.x] = s[0];
}

__global__ void scan_small(u32* __restrict__ partial, u32 NB, u32* __restrict__ total) {
    __shared__ u32 s[256];
    u32 t = threadIdx.x;
    u32 v = (t < NB) ? partial[t] : 0u;
    s[t] = v; __syncthreads();
    for (int d = 1; d < 256; d <<= 1) {
        u32 add = (t >= (u32)d) ? s[t - d] : 0u;
        __syncthreads(); s[t] += add; __syncthreads();
    }
    if (t < NB) partial[t] = s[t] - v;
    if (total && t == 255u) total[0] = s[255];
}

__global__ void scan_apply(const u32* __restrict__ data, u32* __restrict__ out,
                           const u32* __restrict__ partial, u32 G) {
    __shared__ u32 s[256];
    u32 t = threadIdx.x;
    u32 base = blockIdx.x * SCAN_ELEM + t * 8u;
    u32 v[8]; u32 sum = 0;
    #pragma unroll
    for (int j = 0; j < 8; ++j) {
        u32 idx = base + j;
        v[j] = (idx < G) ? data[idx] : 0u;
        sum += v[j];
    }
    s[t] = sum; __syncthreads();
    for (int d = 1; d < 256; d <<= 1) {
        u32 add = (t >= (u32)d) ? s[t - d] : 0u;
        __syncthreads(); s[t] += add; __syncthreads();
    }
    u32 run = s[t] - sum + partial[blockIdx.x];
    #pragma unroll
    for (int j = 0; j < 8; ++j) {
        u32 idx = base + j;
        if (idx < G) { u32 x = v[j]; out[idx] = run; run += x; }
    }
}

// ---- part1: coarse scatter, bases from scanned histmat, LDS cursors only
__global__ void part1(const u32* __restrict__ linrec, const u32* __restrict__ histmat,
                      u32* __restrict__ tmp, int n, u32 NT) {
    __shared__ u32 cur[256];
    int t = threadIdx.x;
    cur[t] = histmat[(u32)t * NT + blockIdx.x];
    __syncthreads();
    u32 base = blockIdx.x * TILE_A;
    u32 m = min((u32)TILE_A, (u32)n - base);
    for (u32 j = t; j < m; j += 256u) {
        u32 rec = linrec[base + j];
        u32 pos = atomicAdd(&cur[rec >> 24], 1u);  // LDS atomic
        tmp[pos] = rec;
    }
}

// ---- part2: one block per coarse bucket -> fine order + bbase
__global__ void part2(const u32* __restrict__ tmp, const u32* __restrict__ histmat,
                      u32* __restrict__ buckrec, u32* __restrict__ bbase, int n, u32 NT) {
    __shared__ u32 h[128], sc[128], cur[128];
    int t = threadIdx.x;
    u32 c = blockIdx.x;
    u32 start = histmat[c * NT];
    u32 end = (c == 255u) ? (u32)n : histmat[(c + 1u) * NT];
    if (t < 128) h[t] = 0;
    __syncthreads();
    for (u32 i = start + t; i < end; i += 256u)
        atomicAdd(&h[(tmp[i] >> 17) & 127u], 1u);
    __syncthreads();
    if (t < 128) sc[t] = h[t];
    __syncthreads();
    for (int d = 1; d < 128; d <<= 1) {
        u32 add = (t < 128 && t >= d) ? sc[t - d] : 0u;
        __syncthreads();
        if (t < 128) sc[t] += add;
        __syncthreads();
    }
    if (t < 128) {
        u32 ex = start + sc[t] - h[t];
        bbase[(c << 7) | (u32)t] = ex;
        cur[t] = ex;
    }
    __syncthreads();
    for (u32 i = start + t; i < end; i += 256u) {
        u32 rec = tmp[i];
        u32 pos = atomicAdd(&cur[(rec >> 17) & 127u], 1u); // LDS atomic
        buckrec[pos] = rec;
    }
}

// ---- fused: bitmap + rank + decoupled-lookback prefix + feats + emit ----
__global__ void __launch_bounds__(256) pass_fused(const u32* __restrict__ buckrec,
        const u32* __restrict__ bbase, const float* __restrict__ kern,
        u64* __restrict__ status, u32* __restrict__ counter,
        float4* __restrict__ rows, float* __restrict__ feats, int n) {
    __shared__ u32 bm[BPB][BWORDS];
    __shared__ u32 wo[BPB][WOPAD];
    __shared__ float fl[BPB][FCAP];
    __shared__ u32 wave_uc[BPB];
    __shared__ u32 blk_base;
    u32 wave = threadIdx.x >> 6, lane = threadIdx.x & 63u;
    u32 bucket = blockIdx.x * BPB + wave;
    u32* B = bm[wave];
    u32* WOF = wo[wave];
    float* F = fl[wave];
    #pragma unroll
    for (int j = 0; j < WPL; ++j) B[lane + 64u * j] = 0u;
    for (u32 j = lane; j < FCAP; j += 64u) F[j] = 0.f;
    __syncthreads();
    u32 start = bbase[bucket];
    u32 end = (bucket + 1 < NBUCK) ? bbase[bucket + 1] : (u32)n;
    for (u32 i = start + lane; i < end; i += 64u) {
        u32 lk = (buckrec[i] >> 3) & LMASK;
        atomicOr(&B[lk >> 5], 1u << (lk & 31u));
    }
    __syncthreads();
    u32 pc[WPL]; u32 sum = 0;
    #pragma unroll
    for (int j = 0; j < WPL; ++j) { pc[j] = __popc(B[lane * WPL + j]); sum += pc[j]; }
    u32 incl = sum;
    #pragma unroll
    for (int d = 1; d < 64; d <<= 1) {
        u32 t = __shfl_up(incl, d);
        if ((int)lane >= d) incl += t;
    }
    u32 lex = incl - sum;                     // lane-exclusive offset within bucket
    u32 e = lex;
    #pragma unroll
    for (int j = 0; j < WPL; ++j) { WOF[woidx(lane * WPL + j)] = e; e += pc[j]; }
    if (lane == 63u) wave_uc[wave] = incl;    // bucket unique count
    __syncthreads();
    // ---- decoupled lookback (thread 0) ----
    if (threadIdx.x == 0) {
        u32 agg = wave_uc[0] + wave_uc[1] + wave_uc[2] + wave_uc[3];
        u32 bid = blockIdx.x;
        u32 excl = 0;
        if (bid == 0) {
            atomicExch(&status[0], ST_PRE | (u64)agg);
        } else {
            atomicExch(&status[bid], ST_AGG | (u64)agg);
            int lb = (int)bid - 1;
            while (lb >= 0) {
                u64 s = atomicAdd(&status[lb], 0ull);     // device-scope atomic load
                u64 st = s & ST_MSK;
                if (st == ST_PRE)      { excl += (u32)s; break; }
                else if (st == ST_AGG) { excl += (u32)s; --lb; }
                else __builtin_amdgcn_s_sleep(1);
            }
            atomicExch(&status[bid], ST_PRE | (u64)(excl + agg));
        }
        blk_base = excl;
        if (bid == NBLK2 - 1) counter[0] = excl + agg;    // total uniques
    }
    __syncthreads();
    u32 base = blk_base;
    for (u32 j = 0; j < wave; ++j) base += wave_uc[j];
    u32 uc = wave_uc[wave];
    bool lds_ok = (uc <= FCAP);
    for (u32 i = start + lane; i < end; i += 64u) {
        u32 rec = buckrec[i];
        u32 off = rec & 7u;
        float contrib = (float)(1u << off) * kern[off];
        u32 lk = (rec >> 3) & LMASK;
        u32 w = lk >> 5, bit = lk & 31u;
        u32 r = WOF[woidx(w)] + (u32)__popc(B[w] & ((1u << bit) - 1u));
        if (lds_ok) atomicAdd(&F[r], contrib);
        else        atomicAdd(&feats[base + r], contrib);   // feats pre-zeroed
    }
    __syncthreads();
    u32 rank = base + lex;
    u32 keyhi = bucket << LBITS;
    #pragma unroll
    for (int j = 0; j < WPL; ++j) {
        u32 bits = B[lane * WPL + j];
        u32 kb = keyhi | ((lane * (u32)WPL + (u32)j) << 5);
        while (bits) {
            u32 t = __builtin_ctz(bits);
            bits &= bits - 1u;
            u32 key = kb | t;
            rows[rank++] = make_float4((float)(key >> 27), (float)(key & 511u),
                                       (float)((key >> 9) & 511u),
                                       (float)((key >> 18) & 511u));
        }
    }
    if (lds_ok) {
        for (u32 j = lane; j < uc; j += 64u) feats[base + j] = F[j];
    }
}

__global__ void pad_fill(float4* __restrict__ rows, const u32* __restrict__ counter, int n) {
    int i = blockIdx.x * blockDim.x + threadIdx.x;
    if (i < n && (u32)i >= counter[0]) rows[i] = make_float4(-1.f, -1.f, -1.f, -1.f);
}

extern "C" void kernel_launch(void* const* d_in, const int* in_sizes, int n_in,
                              void* d_out, int out_size, void* d_ws, size_t ws_size,
                              hipStream_t stream) {
    const int n = in_sizes[0] / 4;               // 4,000,000 points
    const int4* coords = (const int4*)d_in[0];
    const float* kern  = (const float*)d_in[1];
    const u32 NT = ((u32)n + TILE_A - 1) / TILE_A;    // tiles (=489)
    const u32 G1 = 256 * NT;                           // histmat entries
    const u32 NB1 = (G1 + SCAN_ELEM - 1) / SCAN_ELEM;  // 62

    u32* wsp = (u32*)d_ws;
    u32* linrec  = wsp;                    // n   (reused as buckrec by part2)
    u32* tmp     = linrec + n;             // n
    u32* histmat = tmp + n;                // 256*NT
    u32* bbase   = histmat + G1;           // NBUCK
    u32* counter = bbase + NBUCK;          // 1 (+pad)
    u32* spart   = counter + 4;            // 256 scan partials
    u64* status  = (u64*)(spart + 256 + (((size_t)(spart + 256)) & 1 ? 1 : 0)); // NBLK2 u64
    u32* buckrec = linrec;                 // part2 output overwrites linrec

    float4* rows  = (float4*)d_out;                              // n rows
    float*  feats = (float*)((char*)d_out + (size_t)n * 16);     // n fp32

    fill_u32<<<((u32)n + 255) / 256, 256, 0, stream>>>((u32*)feats, 0u, (u32)n);
    fill_u32<<<(NBLK2 * 2 + 255) / 256, 256, 0, stream>>>((u32*)status, 0u, NBLK2 * 2);

    phase_a<<<NT, 256, 0, stream>>>(coords, linrec, histmat, n, NT);
    scan_reduce<<<NB1, 256, 0, stream>>>(histmat, spart, G1);
    scan_small<<<1, 256, 0, stream>>>(spart, NB1, (u32*)nullptr);
    scan_apply<<<NB1, 256, 0, stream>>>(histmat, histmat, spart, G1);
    part1<<<NT, 256, 0, stream>>>(linrec, histmat, tmp, n, NT);
    part2<<<256, 256, 0, stream>>>(tmp, histmat, buckrec, bbase, n, NT);
    pass_fused<<<NBLK2, 256, 0, stream>>>(buckrec, bbase, kern, status, counter,
                                          rows, feats, n);
    pad_fill<<<((u32)n + 255) / 256, 256, 0, stream>>>(rows, counter, n);
}

// Round 9
// 309.719 us; speedup vs baseline: 1.1398x; 1.1398x over previous
//
#include <hip/hip_runtime.h>
#include <stdint.h>

typedef unsigned int u32;
typedef unsigned long long u64;
typedef unsigned short u16;

// key = ((b*512 + z/2)*512 + y/2)*512 + x/2  in [0, 2^29)
// rec = (key<<3)|off. coarse = rec>>24 (8b), fine = (rec>>17)&127 (7b),
// bucket = key>>14 = rec>>17 (15b), local key = key & 0x3FFF (14b).
#define LBITS  14
#define LMASK  ((1u << LBITS) - 1u)
#define NBUCK  (1u << (29 - LBITS))      // 32768 fine buckets
#define BWORDS (1u << (LBITS - 5))       // 512 u32 bitmap words / bucket
#define WPL    (BWORDS / 64)             // 8 words per lane
#define WOPAD  (BWORDS + BWORDS / 32)    // +1 word per 32 -> conflict-free strided scan
#define FCAP   320                       // LDS feats slots per bucket
#define BPB    4                         // buckets (waves) per 256-thr block
#define NBLK2  (NBUCK / BPB)             // fused-pass blocks = 8192
#define TILE_A 8192                      // phase_a / part1 tile
#define SCAN_ELEM 2048                   // hierarchical scan: elems per block

#define ST_AGG (1ull << 62)
#define ST_PRE (2ull << 62)
#define ST_MSK (3ull << 62)

__device__ __forceinline__ u32 woidx(u32 w) { return w + (w >> 5); }

__device__ __forceinline__ u32 make_key(int4 c) {
    return ((((u32)c.x * 512u + ((u32)c.w >> 1)) * 512u + ((u32)c.z >> 1)) * 512u)
           + ((u32)c.y >> 1);
}

__global__ void fill_u32(u32* p, u32 v, u32 n) {
    u32 i = blockIdx.x * blockDim.x + threadIdx.x;
    if (i < n) p[i] = v;
}

// ---- phase A: coords -> linrec + per-tile coarse histogram (bin-major matrix)
__global__ void phase_a(const int4* __restrict__ coords, u32* __restrict__ linrec,
                        u32* __restrict__ histmat, int n, u32 NT) {
    __shared__ u32 h[256];
    int t = threadIdx.x;
    h[t] = 0; __syncthreads();
    u32 base = blockIdx.x * TILE_A;
    u32 m = min((u32)TILE_A, (u32)n - base);
    for (u32 j = t; j < m; j += 256u) {
        int4 c = coords[base + j];
        u32 key = make_key(c);
        u32 off = ((u32)c.y & 1u) | (((u32)c.z & 1u) << 1) | (((u32)c.w & 1u) << 2);
        u32 rec = (key << 3) | off;
        linrec[base + j] = rec;
        atomicAdd(&h[rec >> 24], 1u);
    }
    __syncthreads();
    histmat[(u32)t * NT + blockIdx.x] = h[t];   // bin-major: scan order = radix order
}

// ---- hierarchical exclusive scan: reduce -> small scan -> apply ----
__global__ void scan_reduce(const u32* __restrict__ data, u32* __restrict__ partial, u32 G) {
    __shared__ u32 s[256];
    u32 t = threadIdx.x;
    u32 base = blockIdx.x * SCAN_ELEM + t * 8u;
    u32 sum = 0;
    #pragma unroll
    for (int j = 0; j < 8; ++j) { u32 idx = base + j; if (idx < G) sum += data[idx]; }
    s[t] = sum; __syncthreads();
    for (int d = 128; d > 0; d >>= 1) { if ((int)t < d) s[t] += s[t + d]; __syncthreads(); }
    if (t == 0) partial[blockIdx.x] = s[0];
}

__global__ void scan_small(u32* __restrict__ partial, u32 NB) {
    __shared__ u32 s[256];
    u32 t = threadIdx.x;
    u32 v = (t < NB) ? partial[t] : 0u;
    s[t] = v; __syncthreads();
    for (int d = 1; d < 256; d <<= 1) {
        u32 add = (t >= (u32)d) ? s[t - d] : 0u;
        __syncthreads(); s[t] += add; __syncthreads();
    }
    if (t < NB) partial[t] = s[t] - v;
}

__global__ void scan_apply(const u32* __restrict__ data, u32* __restrict__ out,
                           const u32* __restrict__ partial, u32 G) {
    __shared__ u32 s[256];
    u32 t = threadIdx.x;
    u32 base = blockIdx.x * SCAN_ELEM + t * 8u;
    u32 v[8]; u32 sum = 0;
    #pragma unroll
    for (int j = 0; j < 8; ++j) {
        u32 idx = base + j;
        v[j] = (idx < G) ? data[idx] : 0u;
        sum += v[j];
    }
    s[t] = sum; __syncthreads();
    for (int d = 1; d < 256; d <<= 1) {
        u32 add = (t >= (u32)d) ? s[t - d] : 0u;
        __syncthreads(); s[t] += add; __syncthreads();
    }
    u32 run = s[t] - sum + partial[blockIdx.x];
    #pragma unroll
    for (int j = 0; j < 8; ++j) {
        u32 idx = base + j;
        if (idx < G) { u32 x = v[j]; out[idx] = run; run += x; }
    }
}

// ---- part1: coarse scatter, bases from scanned histmat, LDS cursors only
__global__ void part1(const u32* __restrict__ linrec, const u32* __restrict__ histmat,
                      u32* __restrict__ tmp, int n, u32 NT) {
    __shared__ u32 cur[256];
    int t = threadIdx.x;
    cur[t] = histmat[(u32)t * NT + blockIdx.x];
    __syncthreads();
    u32 base = blockIdx.x * TILE_A;
    u32 m = min((u32)TILE_A, (u32)n - base);
    for (u32 j = t; j < m; j += 256u) {
        u32 rec = linrec[base + j];
        u32 pos = atomicAdd(&cur[rec >> 24], 1u);  // LDS atomic
        tmp[pos] = rec;
    }
}

// ---- part2: one block per coarse bucket -> fine order + bbase
__global__ void part2(const u32* __restrict__ tmp, const u32* __restrict__ histmat,
                      u32* __restrict__ buckrec, u32* __restrict__ bbase, int n, u32 NT) {
    __shared__ u32 h[128], sc[128], cur[128];
    int t = threadIdx.x;
    u32 c = blockIdx.x;
    u32 start = histmat[c * NT];
    u32 end = (c == 255u) ? (u32)n : histmat[(c + 1u) * NT];
    if (t < 128) h[t] = 0;
    __syncthreads();
    for (u32 i = start + t; i < end; i += 256u)
        atomicAdd(&h[(tmp[i] >> 17) & 127u], 1u);
    __syncthreads();
    if (t < 128) sc[t] = h[t];
    __syncthreads();
    for (int d = 1; d < 128; d <<= 1) {
        u32 add = (t < 128 && t >= d) ? sc[t - d] : 0u;
        __syncthreads();
        if (t < 128) sc[t] += add;
        __syncthreads();
    }
    if (t < 128) {
        u32 ex = start + sc[t] - h[t];
        bbase[(c << 7) | (u32)t] = ex;
        cur[t] = ex;
    }
    __syncthreads();
    for (u32 i = start + t; i < end; i += 256u) {
        u32 rec = tmp[i];
        u32 pos = atomicAdd(&cur[(rec >> 17) & 127u], 1u); // LDS atomic
        buckrec[pos] = rec;
    }
}

// ---- fused: bitmap + rank + wave-parallel decoupled lookback + feats + emit + pad
__global__ void __launch_bounds__(256) pass_fused(const u32* __restrict__ buckrec,
        const u32* __restrict__ bbase, const float* __restrict__ kern,
        u64* __restrict__ status, float4* __restrict__ rows,
        float* __restrict__ feats, int n) {
    __shared__ u32 bm[BPB][WOPAD];
    __shared__ u32 wo[BPB][WOPAD];
    __shared__ float fl[BPB][FCAP];
    __shared__ u32 wave_uc[BPB];
    __shared__ u32 blk_base;
    u32 wave = threadIdx.x >> 6, lane = threadIdx.x & 63u;
    u32 bucket = blockIdx.x * BPB + wave;
    u32* B = bm[wave];
    u32* WOF = wo[wave];
    float* F = fl[wave];
    #pragma unroll
    for (int j = 0; j < WPL; ++j) B[woidx(lane * WPL + j)] = 0u;
    for (u32 j = lane; j < FCAP; j += 64u) F[j] = 0.f;
    __syncthreads();
    u32 start = bbase[bucket];
    u32 end = (bucket + 1 < NBUCK) ? bbase[bucket + 1] : (u32)n;
    for (u32 i = start + lane; i < end; i += 64u) {
        u32 lk = (buckrec[i] >> 3) & LMASK;
        atomicOr(&B[woidx(lk >> 5)], 1u << (lk & 31u));
    }
    __syncthreads();
    u32 pc[WPL]; u32 sum = 0;
    #pragma unroll
    for (int j = 0; j < WPL; ++j) { pc[j] = __popc(B[woidx(lane * WPL + j)]); sum += pc[j]; }
    u32 incl = sum;
    #pragma unroll
    for (int d = 1; d < 64; d <<= 1) {
        u32 t = __shfl_up(incl, d);
        if ((int)lane >= d) incl += t;
    }
    u32 lex = incl - sum;                     // lane-exclusive offset within bucket
    u32 e = lex;
    #pragma unroll
    for (int j = 0; j < WPL; ++j) { WOF[woidx(lane * WPL + j)] = e; e += pc[j]; }
    if (lane == 63u) wave_uc[wave] = incl;    // bucket unique count
    __syncthreads();
    u32 agg = wave_uc[0] + wave_uc[1] + wave_uc[2] + wave_uc[3];
    if (threadIdx.x == 0) {
        if (blockIdx.x == 0) { atomicExch(&status[0], ST_PRE | (u64)agg); blk_base = 0; }
        else                 { atomicExch(&status[blockIdx.x], ST_AGG | (u64)agg); }
    }
    __syncthreads();
    // ---- wave-parallel lookback (wave 0): 64 statuses per step ----
    if (blockIdx.x > 0 && wave == 0) {
        u32 excl = 0;
        int winend = (int)blockIdx.x - 1;
        for (;;) {
            int idx = winend - (int)lane;
            u64 s = ST_PRE;                          // idx<0 => prefix 0
            if (idx >= 0) {
                s = atomicAdd(&status[idx], 0ull);
                while ((s & ST_MSK) == 0ull) {
                    __builtin_amdgcn_s_sleep(1);
                    s = atomicAdd(&status[idx], 0ull);
                }
            }
            u64 pre = __ballot((s & ST_MSK) == ST_PRE);
            u32 contrib;
            if (pre) {
                u32 f = (u32)__ffsll((unsigned long long)pre) - 1u;  // closest PREFIX
                contrib = (lane <= f) ? (u32)s : 0u;
            } else {
                contrib = (u32)s;                    // all AGG: take them all
            }
            #pragma unroll
            for (int d2 = 32; d2 > 0; d2 >>= 1) contrib += __shfl_down(contrib, d2);
            excl += __shfl(contrib, 0);
            if (pre) break;
            winend -= 64;
        }
        if (lane == 0) {
            atomicExch(&status[blockIdx.x], ST_PRE | (u64)(excl + agg));
            blk_base = excl;
        }
    }
    __syncthreads();
    u32 base = blk_base;
    for (u32 j = 0; j < wave; ++j) base += wave_uc[j];
    u32 uc = wave_uc[wave];
    bool lds_ok = (uc <= FCAP);
    for (u32 i = start + lane; i < end; i += 64u) {
        u32 rec = buckrec[i];
        u32 off = rec & 7u;
        float contrib = (float)(1u << off) * kern[off];
        u32 lk = (rec >> 3) & LMASK;
        u32 w = lk >> 5, bit = lk & 31u;
        u32 r = WOF[woidx(w)] + (u32)__popc(B[woidx(w)] & ((1u << bit) - 1u));
        if (lds_ok) atomicAdd(&F[r], contrib);
        else        atomicAdd(&feats[base + r], contrib);   // feats pre-zeroed
    }
    __syncthreads();
    u32 rank = base + lex;
    u32 keyhi = bucket << LBITS;
    #pragma unroll
    for (int j = 0; j < WPL; ++j) {
        u32 bits = B[woidx(lane * WPL + j)];
        u32 kb = keyhi | ((lane * (u32)WPL + (u32)j) << 5);
        while (bits) {
            u32 t = __builtin_ctz(bits);
            bits &= bits - 1u;
            u32 key = kb | t;
            rows[rank++] = make_float4((float)(key >> 27), (float)(key & 511u),
                                       (float)((key >> 9) & 511u),
                                       (float)((key >> 18) & 511u));
        }
    }
    if (lds_ok) {
        for (u32 j = lane; j < uc; j += 64u) feats[base + j] = F[j];
    }
    // last block pads rows [U, n) — cannot race: all rank writes are < U
    if (blockIdx.x == NBLK2 - 1) {
        u32 U = blk_base + agg;
        for (u32 i = U + threadIdx.x; i < (u32)n; i += 256u)
            rows[i] = make_float4(-1.f, -1.f, -1.f, -1.f);
    }
}

extern "C" void kernel_launch(void* const* d_in, const int* in_sizes, int n_in,
                              void* d_out, int out_size, void* d_ws, size_t ws_size,
                              hipStream_t stream) {
    const int n = in_sizes[0] / 4;               // 4,000,000 points
    const int4* coords = (const int4*)d_in[0];
    const float* kern  = (const float*)d_in[1];
    const u32 NT = ((u32)n + TILE_A - 1) / TILE_A;    // tiles (=489)
    const u32 G1 = 256 * NT;                           // histmat entries
    const u32 NB1 = (G1 + SCAN_ELEM - 1) / SCAN_ELEM;  // 62

    u64* status  = (u64*)d_ws;             // NBLK2 u64 (8-aligned at ws base)
    u32* wsp     = (u32*)(status + NBLK2);
    u32* linrec  = wsp;                    // n   (reused as buckrec by part2)
    u32* tmp     = linrec + n;             // n
    u32* histmat = tmp + n;                // 256*NT
    u32* bbase   = histmat + G1;           // NBUCK
    u32* spart   = bbase + NBUCK;          // 256 scan partials
    u32* buckrec = linrec;                 // part2 output overwrites linrec

    float4* rows  = (float4*)d_out;                              // n rows
    float*  feats = (float*)((char*)d_out + (size_t)n * 16);     // n fp32

    fill_u32<<<((u32)n + 255) / 256, 256, 0, stream>>>((u32*)feats, 0u, (u32)n);
    fill_u32<<<(NBLK2 * 2 + 255) / 256, 256, 0, stream>>>((u32*)status, 0u, NBLK2 * 2);

    phase_a<<<NT, 256, 0, stream>>>(coords, linrec, histmat, n, NT);
    scan_reduce<<<NB1, 256, 0, stream>>>(histmat, spart, G1);
    scan_small<<<1, 256, 0, stream>>>(spart, NB1);
    scan_apply<<<NB1, 256, 0, stream>>>(histmat, histmat, spart, G1);
    part1<<<NT, 256, 0, stream>>>(linrec, histmat, tmp, n, NT);
    part2<<<256, 256, 0, stream>>>(tmp, histmat, buckrec, bbase, n, NT);
    pass_fused<<<NBLK2, 256, 0, stream>>>(buckrec, bbase, kern, status, rows, feats, n);
}

// Round 10
// 292.729 us; speedup vs baseline: 1.2060x; 1.0580x over previous
//
#include <hip/hip_runtime.h>
#include <stdint.h>

typedef unsigned int u32;
typedef unsigned long long u64;

// key = ((b*512 + z/2)*512 + y/2)*512 + x/2  in [0, 2^29)
// rec = (key<<3)|off. coarse = rec>>24 (8b), fine = (rec>>17)&127 (7b),
// bucket = key>>14 = rec>>17 (15b), local key = key & 0x3FFF (14b).
#define LBITS  14
#define LMASK  ((1u << LBITS) - 1u)
#define NBUCK  (1u << (29 - LBITS))      // 32768 fine buckets
#define BWORDS (1u << (LBITS - 5))       // 512 u32 bitmap words / bucket
#define WPL    (BWORDS / 64)             // 8 words per lane
#define WOPAD  (BWORDS + BWORDS / 32)    // +1 word per 32 -> conflict-free strided access
#define FCAP   320                       // LDS feats slots per bucket (mean uc ~122)
#define BPB    4                         // buckets (waves) per 256-thr block
#define TILE_A 2048                      // phase_a / part1 tile (8 rec/thread)
#define S2     16                        // chunks per coarse bucket in part2
#define SCAN_ELEM 2048

__device__ __forceinline__ u32 woidx(u32 w) { return w + (w >> 5); }

__device__ __forceinline__ u32 make_key(int4 c) {
    return ((((u32)c.x * 512u + ((u32)c.w >> 1)) * 512u + ((u32)c.z >> 1)) * 512u)
           + ((u32)c.y >> 1);
}

__global__ void fill_u32x4(uint4* p, u32 n4) {
    u32 i = blockIdx.x * blockDim.x + threadIdx.x;
    if (i < n4) p[i] = make_uint4(0u, 0u, 0u, 0u);
}

// ---- phase A: coords -> linrec + per-tile coarse histogram (bin-major matrix)
__global__ void __launch_bounds__(256) phase_a(const int4* __restrict__ coords,
        u32* __restrict__ linrec, u32* __restrict__ histmat, int n, u32 NT) {
    __shared__ u32 h[4 * 256];
    u32 t = threadIdx.x, wave = t >> 6;
    for (u32 j = t; j < 1024u; j += 256u) h[j] = 0u;
    __syncthreads();
    u32 base = blockIdx.x * TILE_A;
    u32 m = min((u32)TILE_A, (u32)n - base);
    for (u32 j = t; j < m; j += 256u) {
        int4 c = coords[base + j];
        u32 key = make_key(c);
        u32 off = ((u32)c.y & 1u) | (((u32)c.z & 1u) << 1) | (((u32)c.w & 1u) << 2);
        u32 rec = (key << 3) | off;
        linrec[base + j] = rec;
        atomicAdd(&h[wave * 256u + (rec >> 24)], 1u);
    }
    __syncthreads();
    histmat[t * NT + blockIdx.x] = h[t] + h[256u + t] + h[512u + t] + h[768u + t];
}

// ---- hierarchical exclusive scan: reduce -> small scan -> apply ----
__global__ void scan_reduce(const u32* __restrict__ data, u32* __restrict__ partial, u32 G) {
    __shared__ u32 s[256];
    u32 t = threadIdx.x;
    u32 base = blockIdx.x * SCAN_ELEM + t * 8u;
    u32 sum = 0;
    #pragma unroll
    for (int j = 0; j < 8; ++j) { u32 idx = base + j; if (idx < G) sum += data[idx]; }
    s[t] = sum; __syncthreads();
    for (int d = 128; d > 0; d >>= 1) { if ((int)t < d) s[t] += s[t + d]; __syncthreads(); }
    if (t == 0) partial[blockIdx.x] = s[0];
}

__global__ void scan_small(u32* __restrict__ partial, u32 NB, u32* __restrict__ total) {
    __shared__ u32 s[256];
    u32 t = threadIdx.x;
    u32 v = (t < NB) ? partial[t] : 0u;
    s[t] = v; __syncthreads();
    for (int d = 1; d < 256; d <<= 1) {
        u32 add = (t >= (u32)d) ? s[t - d] : 0u;
        __syncthreads(); s[t] += add; __syncthreads();
    }
    if (t < NB) partial[t] = s[t] - v;
    if (total && t == 255u) total[0] = s[255];
}

__global__ void scan_apply(const u32* __restrict__ data, u32* __restrict__ out,
                           const u32* __restrict__ partial, u32 G) {
    __shared__ u32 s[256];
    u32 t = threadIdx.x;
    u32 base = blockIdx.x * SCAN_ELEM + t * 8u;
    u32 v[8]; u32 sum = 0;
    #pragma unroll
    for (int j = 0; j < 8; ++j) {
        u32 idx = base + j;
        v[j] = (idx < G) ? data[idx] : 0u;
        sum += v[j];
    }
    s[t] = sum; __syncthreads();
    for (int d = 1; d < 256; d <<= 1) {
        u32 add = (t >= (u32)d) ? s[t - d] : 0u;
        __syncthreads(); s[t] += add; __syncthreads();
    }
    u32 run = s[t] - sum + partial[blockIdx.x];
    #pragma unroll
    for (int j = 0; j < 8; ++j) {
        u32 idx = base + j;
        if (idx < G) { u32 x = v[j]; out[idx] = run; run += x; }
    }
}

// ---- part1: coarse scatter, bases from scanned histmat, LDS cursors only
__global__ void __launch_bounds__(256) part1(const u32* __restrict__ linrec,
        const u32* __restrict__ histmat, u32* __restrict__ tmp, int n, u32 NT) {
    __shared__ u32 cur[256];
    u32 t = threadIdx.x;
    cur[t] = histmat[t * NT + blockIdx.x];
    __syncthreads();
    u32 base = blockIdx.x * TILE_A;
    u32 m = min((u32)TILE_A, (u32)n - base);
    for (u32 j = t; j < m; j += 256u) {
        u32 rec = linrec[base + j];
        u32 pos = atomicAdd(&cur[rec >> 24], 1u);  // LDS atomic
        tmp[pos] = rec;
    }
}

// ---- part2a: per (coarse, chunk) 128-bin fine histogram -> hist2[(c*128+f)*16+s]
__global__ void __launch_bounds__(256) part2a(const u32* __restrict__ tmp,
        const u32* __restrict__ histmat, u32* __restrict__ hist2, int n, u32 NT) {
    __shared__ u32 h[4 * 128];
    u32 t = threadIdx.x, wave = t >> 6;
    u32 c = blockIdx.x >> 4, s = blockIdx.x & 15u;
    for (u32 j = t; j < 512u; j += 256u) h[j] = 0u;
    __syncthreads();
    u32 cs = histmat[c * NT];
    u32 ce = (c == 255u) ? (u32)n : histmat[(c + 1u) * NT];
    u32 L = ce - cs;
    u32 lo = cs + L * s / S2, hi = cs + L * (s + 1u) / S2;
    for (u32 i = lo + t; i < hi; i += 256u)
        atomicAdd(&h[wave * 128u + ((tmp[i] >> 17) & 127u)], 1u);
    __syncthreads();
    if (t < 128u)
        hist2[((c * 128u + t) * S2) + s] = h[t] + h[128u + t] + h[256u + t] + h[384u + t];
}

// ---- part2b: scatter chunk into fine-bucket order using scanned hist2 bases
__global__ void __launch_bounds__(256) part2b(const u32* __restrict__ tmp,
        const u32* __restrict__ histmat, const u32* __restrict__ hist2,
        u32* __restrict__ buckrec, int n, u32 NT) {
    __shared__ u32 cur[128];
    u32 t = threadIdx.x;
    u32 c = blockIdx.x >> 4, s = blockIdx.x & 15u;
    if (t < 128u) cur[t] = hist2[((c * 128u + t) * S2) + s];
    __syncthreads();
    u32 cs = histmat[c * NT];
    u32 ce = (c == 255u) ? (u32)n : histmat[(c + 1u) * NT];
    u32 L = ce - cs;
    u32 lo = cs + L * s / S2, hi = cs + L * (s + 1u) / S2;
    for (u32 i = lo + t; i < hi; i += 256u) {
        u32 rec = tmp[i];
        u32 pos = atomicAdd(&cur[(rec >> 17) & 127u], 1u);  // LDS atomic
        buckrec[pos] = rec;
    }
}

// ---- one wave per fine bucket: padded LDS bitmap -> unique count
__global__ void __launch_bounds__(256) pass_count(const u32* __restrict__ buckrec,
        const u32* __restrict__ hist2, u32* __restrict__ ucount, int n) {
    __shared__ u32 bm[BPB][WOPAD];
    u32 wave = threadIdx.x >> 6, lane = threadIdx.x & 63u;
    u32 bucket = blockIdx.x * BPB + wave;
    u32* B = bm[wave];
    #pragma unroll
    for (int j = 0; j < WPL; ++j) B[woidx(lane * WPL + j)] = 0u;
    __syncthreads();
    u32 start = hist2[bucket * S2];
    u32 end = (bucket + 1u < NBUCK) ? hist2[(bucket + 1u) * S2] : (u32)n;
    for (u32 i = start + lane; i < end; i += 64u) {
        u32 lk = (buckrec[i] >> 3) & LMASK;
        atomicOr(&B[woidx(lk >> 5)], 1u << (lk & 31u));
    }
    __syncthreads();
    u32 sum = 0;
    #pragma unroll
    for (int j = 0; j < WPL; ++j) sum += __popc(B[woidx(lane * WPL + j)]);
    u32 incl = sum;
    #pragma unroll
    for (int d = 1; d < 64; d <<= 1) {
        u32 t = __shfl_up(incl, d);
        if ((int)lane >= d) incl += t;
    }
    if (lane == 63u) ucount[bucket] = incl;
}

// ---- one wave per fine bucket: rank + feats in LDS, emit rows in key order
__global__ void __launch_bounds__(256) pass_emit(const u32* __restrict__ buckrec,
        const u32* __restrict__ hist2, const u32* __restrict__ ubase,
        const float* __restrict__ kern, float4* __restrict__ rows,
        float* __restrict__ feats, int n) {
    __shared__ u32 bm[BPB][WOPAD];
    __shared__ u32 wo[BPB][WOPAD];
    __shared__ float fl[BPB][FCAP];
    u32 wave = threadIdx.x >> 6, lane = threadIdx.x & 63u;
    u32 bucket = blockIdx.x * BPB + wave;
    u32* B = bm[wave];
    u32* WOF = wo[wave];
    float* F = fl[wave];
    #pragma unroll
    for (int j = 0; j < WPL; ++j) B[woidx(lane * WPL + j)] = 0u;
    for (u32 j = lane; j < FCAP; j += 64u) F[j] = 0.f;
    __syncthreads();
    u32 start = hist2[bucket * S2];
    u32 end = (bucket + 1u < NBUCK) ? hist2[(bucket + 1u) * S2] : (u32)n;
    for (u32 i = start + lane; i < end; i += 64u) {
        u32 lk = (buckrec[i] >> 3) & LMASK;
        atomicOr(&B[woidx(lk >> 5)], 1u << (lk & 31u));
    }
    __syncthreads();
    u32 pc[WPL]; u32 sum = 0;
    #pragma unroll
    for (int j = 0; j < WPL; ++j) { pc[j] = __popc(B[woidx(lane * WPL + j)]); sum += pc[j]; }
    u32 incl = sum;
    #pragma unroll
    for (int d = 1; d < 64; d <<= 1) {
        u32 t = __shfl_up(incl, d);
        if ((int)lane >= d) incl += t;
    }
    u32 lex = incl - sum;                 // lane-exclusive unique offset in bucket
    u32 uc = __shfl(incl, 63);            // bucket total uniques
    u32 e = lex;
    #pragma unroll
    for (int j = 0; j < WPL; ++j) { WOF[woidx(lane * WPL + j)] = e; e += pc[j]; }
    __syncthreads();
    u32 base = ubase[bucket];
    bool lds_ok = (uc <= FCAP);
    for (u32 i = start + lane; i < end; i += 64u) {
        u32 rec = buckrec[i];
        u32 off = rec & 7u;
        float contrib = (float)(1u << off) * kern[off];
        u32 lk = (rec >> 3) & LMASK;
        u32 w = lk >> 5, bit = lk & 31u;
        u32 r = WOF[woidx(w)] + (u32)__popc(B[woidx(w)] & ((1u << bit) - 1u));
        if (lds_ok) atomicAdd(&F[r], contrib);
        else        atomicAdd(&feats[base + r], contrib);   // feats pre-zeroed
    }
    __syncthreads();
    u32 rank = base + lex;
    u32 keyhi = bucket << LBITS;
    #pragma unroll
    for (int j = 0; j < WPL; ++j) {
        u32 bits = B[woidx(lane * WPL + j)];
        u32 kb = keyhi | ((lane * (u32)WPL + (u32)j) << 5);
        while (bits) {
            u32 t = __builtin_ctz(bits);
            bits &= bits - 1u;
            u32 key = kb | t;
            rows[rank++] = make_float4((float)(key >> 27), (float)(key & 511u),
                                       (float)((key >> 9) & 511u),
                                       (float)((key >> 18) & 511u));
        }
    }
    if (lds_ok) {
        for (u32 j = lane; j < uc; j += 64u) feats[base + j] = F[j];
    }
}

__global__ void pad_fill(float4* __restrict__ rows, const u32* __restrict__ counter, int n) {
    int i = blockIdx.x * blockDim.x + threadIdx.x;
    if (i < n && (u32)i >= counter[0]) rows[i] = make_float4(-1.f, -1.f, -1.f, -1.f);
}

extern "C" void kernel_launch(void* const* d_in, const int* in_sizes, int n_in,
                              void* d_out, int out_size, void* d_ws, size_t ws_size,
                              hipStream_t stream) {
    const int n = in_sizes[0] / 4;               // 4,000,000 points
    const int4* coords = (const int4*)d_in[0];
    const float* kern  = (const float*)d_in[1];
    const u32 NT = ((u32)n + TILE_A - 1) / TILE_A;        // 1954 tiles
    const u32 G1 = 256 * NT;                               // histmat entries (500224)
    const u32 G2 = 256 * 128 * S2;                         // hist2 entries (524288)
    const u32 NB1 = (G1 + SCAN_ELEM - 1) / SCAN_ELEM;      // 245
    const u32 NB2 = (G2 + SCAN_ELEM - 1) / SCAN_ELEM;      // 256
    const u32 NB3 = (NBUCK + SCAN_ELEM - 1) / SCAN_ELEM;   // 16

    u32* wsp = (u32*)d_ws;
    u32* linrec  = wsp;                    // n  (reused as buckrec by part2b)
    u32* tmp     = linrec + n;             // n  (coarse-ordered records)
    u32* histmat = tmp + n;                // G1
    u32* hist2   = histmat + G1;           // G2
    u32* ucount  = hist2 + G2;             // NBUCK (scanned in place -> ubase)
    u32* counter = ucount + NBUCK;         // 4
    u32* spart   = counter + 4;            // 256
    u32* buckrec = linrec;

    float4* rows  = (float4*)d_out;                              // n rows
    float*  feats = (float*)((char*)d_out + (size_t)n * 16);     // n fp32

    fill_u32x4<<<((u32)n / 4 + 255) / 256, 256, 0, stream>>>((uint4*)feats, (u32)n / 4);

    phase_a<<<NT, 256, 0, stream>>>(coords, linrec, histmat, n, NT);
    scan_reduce<<<NB1, 256, 0, stream>>>(histmat, spart, G1);
    scan_small<<<1, 256, 0, stream>>>(spart, NB1, (u32*)nullptr);
    scan_apply<<<NB1, 256, 0, stream>>>(histmat, histmat, spart, G1);
    part1<<<NT, 256, 0, stream>>>(linrec, histmat, tmp, n, NT);
    part2a<<<256 * S2, 256, 0, stream>>>(tmp, histmat, hist2, n, NT);
    scan_reduce<<<NB2, 256, 0, stream>>>(hist2, spart, G2);
    scan_small<<<1, 256, 0, stream>>>(spart, NB2, (u32*)nullptr);
    scan_apply<<<NB2, 256, 0, stream>>>(hist2, hist2, spart, G2);
    part2b<<<256 * S2, 256, 0, stream>>>(tmp, histmat, hist2, buckrec, n, NT);
    pass_count<<<NBUCK / BPB, 256, 0, stream>>>(buckrec, hist2, ucount, n);
    scan_reduce<<<NB3, 256, 0, stream>>>(ucount, spart, NBUCK);
    scan_small<<<1, 256, 0, stream>>>(spart, NB3, counter);
    scan_apply<<<NB3, 256, 0, stream>>>(ucount, ucount, spart, NBUCK);
    pass_emit<<<NBUCK / BPB, 256, 0, stream>>>(buckrec, hist2, ucount, kern,
                                               rows, feats, n);
    pad_fill<<<((u32)n + 255) / 256, 256, 0, stream>>>(rows, counter, n);
}

// Round 11
// 279.213 us; speedup vs baseline: 1.2643x; 1.0484x over previous
//
#include <hip/hip_runtime.h>
#include <stdint.h>

typedef unsigned int u32;
typedef unsigned long long u64;

// key = ((b*512 + z/2)*512 + y/2)*512 + x/2  in [0, 2^29)
// rec = (key<<3)|off. coarse = rec>>24 (8b), fine = (rec>>17)&127 (7b),
// bucket = key>>14 = rec>>17 (15b), local key = key & 0x3FFF (14b).
#define LBITS  14
#define LMASK  ((1u << LBITS) - 1u)
#define NBUCK  (1u << (29 - LBITS))      // 32768 fine buckets
#define BWORDS (1u << (LBITS - 5))       // 512 u32 bitmap words / bucket
#define WPL    (BWORDS / 64)             // 8 words per lane (one prefix group)
#define WOPAD  (BWORDS + BWORDS / 32)    // +1 word per 32 -> conflict-free strided access
#define FCAP   256                       // LDS feats slots per bucket (mean uc ~122)
#define BPB    4                         // buckets (waves) per 256-thr block
#define TILE_A 4096                      // phase_a / part1 tile (16 rec/thread)
#define S2     8                         // chunks per coarse bucket in part2
#define SCAN_ELEM 2048

__device__ __forceinline__ u32 woidx(u32 w) { return w + (w >> 5); }

__device__ __forceinline__ u32 make_key(int4 c) {
    return ((((u32)c.x * 512u + ((u32)c.w >> 1)) * 512u + ((u32)c.z >> 1)) * 512u)
           + ((u32)c.y >> 1);
}

// ---- phase A: coords -> linrec + per-tile coarse histogram (bin-major matrix)
__global__ void __launch_bounds__(256) phase_a(const int4* __restrict__ coords,
        u32* __restrict__ linrec, u32* __restrict__ histmat, int n, u32 NT) {
    __shared__ u32 h[4 * 256];
    u32 t = threadIdx.x, wave = t >> 6;
    for (u32 j = t; j < 1024u; j += 256u) h[j] = 0u;
    __syncthreads();
    u32 base = blockIdx.x * TILE_A;
    u32 m = min((u32)TILE_A, (u32)n - base);
    for (u32 j = t; j < m; j += 256u) {
        int4 c = coords[base + j];
        u32 key = make_key(c);
        u32 off = ((u32)c.y & 1u) | (((u32)c.z & 1u) << 1) | (((u32)c.w & 1u) << 2);
        u32 rec = (key << 3) | off;
        linrec[base + j] = rec;
        atomicAdd(&h[wave * 256u + (rec >> 24)], 1u);
    }
    __syncthreads();
    histmat[t * NT + blockIdx.x] = h[t] + h[256u + t] + h[512u + t] + h[768u + t];
}

// ---- hierarchical exclusive scan: reduce -> small scan -> apply ----
__global__ void scan_reduce(const u32* __restrict__ data, u32* __restrict__ partial, u32 G) {
    __shared__ u32 s[256];
    u32 t = threadIdx.x;
    u32 base = blockIdx.x * SCAN_ELEM + t * 8u;
    u32 sum = 0;
    #pragma unroll
    for (int j = 0; j < 8; ++j) { u32 idx = base + j; if (idx < G) sum += data[idx]; }
    s[t] = sum; __syncthreads();
    for (int d = 128; d > 0; d >>= 1) { if ((int)t < d) s[t] += s[t + d]; __syncthreads(); }
    if (t == 0) partial[blockIdx.x] = s[0];
}

__global__ void scan_small(u32* __restrict__ partial, u32 NB, u32* __restrict__ total) {
    __shared__ u32 s[256];
    u32 t = threadIdx.x;
    u32 v = (t < NB) ? partial[t] : 0u;
    s[t] = v; __syncthreads();
    for (int d = 1; d < 256; d <<= 1) {
        u32 add = (t >= (u32)d) ? s[t - d] : 0u;
        __syncthreads(); s[t] += add; __syncthreads();
    }
    if (t < NB) partial[t] = s[t] - v;
    if (total && t == 255u) total[0] = s[255];
}

__global__ void scan_apply(const u32* __restrict__ data, u32* __restrict__ out,
                           const u32* __restrict__ partial, u32 G) {
    __shared__ u32 s[256];
    u32 t = threadIdx.x;
    u32 base = blockIdx.x * SCAN_ELEM + t * 8u;
    u32 v[8]; u32 sum = 0;
    #pragma unroll
    for (int j = 0; j < 8; ++j) {
        u32 idx = base + j;
        v[j] = (idx < G) ? data[idx] : 0u;
        sum += v[j];
    }
    s[t] = sum; __syncthreads();
    for (int d = 1; d < 256; d <<= 1) {
        u32 add = (t >= (u32)d) ? s[t - d] : 0u;
        __syncthreads(); s[t] += add; __syncthreads();
    }
    u32 run = s[t] - sum + partial[blockIdx.x];
    #pragma unroll
    for (int j = 0; j < 8; ++j) {
        u32 idx = base + j;
        if (idx < G) { u32 x = v[j]; out[idx] = run; run += x; }
    }
}

// ---- part1: coarse scatter, bases from scanned histmat, LDS cursors only
__global__ void __launch_bounds__(256) part1(const u32* __restrict__ linrec,
        const u32* __restrict__ histmat, u32* __restrict__ tmp, int n, u32 NT) {
    __shared__ u32 cur[256];
    u32 t = threadIdx.x;
    cur[t] = histmat[t * NT + blockIdx.x];
    __syncthreads();
    u32 base = blockIdx.x * TILE_A;
    u32 m = min((u32)TILE_A, (u32)n - base);
    for (u32 j = t; j < m; j += 256u) {
        u32 rec = linrec[base + j];
        u32 pos = atomicAdd(&cur[rec >> 24], 1u);  // LDS atomic
        tmp[pos] = rec;
    }
}

// ---- part2a: per (coarse, chunk) 128-bin fine histogram -> hist2[(c*128+f)*S2+s]
__global__ void __launch_bounds__(256) part2a(const u32* __restrict__ tmp,
        const u32* __restrict__ histmat, u32* __restrict__ hist2, int n, u32 NT) {
    __shared__ u32 h[4 * 128];
    u32 t = threadIdx.x, wave = t >> 6;
    u32 c = blockIdx.x / S2, s = blockIdx.x % S2;
    for (u32 j = t; j < 512u; j += 256u) h[j] = 0u;
    __syncthreads();
    u32 cs = histmat[c * NT];
    u32 ce = (c == 255u) ? (u32)n : histmat[(c + 1u) * NT];
    u32 L = ce - cs;
    u32 lo = cs + L * s / S2, hi = cs + L * (s + 1u) / S2;
    for (u32 i = lo + t; i < hi; i += 256u)
        atomicAdd(&h[wave * 128u + ((tmp[i] >> 17) & 127u)], 1u);
    __syncthreads();
    if (t < 128u)
        hist2[((c * 128u + t) * S2) + s] = h[t] + h[128u + t] + h[256u + t] + h[384u + t];
}

// ---- part2b: scatter chunk into fine-bucket order using scanned hist2 bases
__global__ void __launch_bounds__(256) part2b(const u32* __restrict__ tmp,
        const u32* __restrict__ histmat, const u32* __restrict__ hist2,
        u32* __restrict__ buckrec, int n, u32 NT) {
    __shared__ u32 cur[128];
    u32 t = threadIdx.x;
    u32 c = blockIdx.x / S2, s = blockIdx.x % S2;
    if (t < 128u) cur[t] = hist2[((c * 128u + t) * S2) + s];
    __syncthreads();
    u32 cs = histmat[c * NT];
    u32 ce = (c == 255u) ? (u32)n : histmat[(c + 1u) * NT];
    u32 L = ce - cs;
    u32 lo = cs + L * s / S2, hi = cs + L * (s + 1u) / S2;
    for (u32 i = lo + t; i < hi; i += 256u) {
        u32 rec = tmp[i];
        u32 pos = atomicAdd(&cur[(rec >> 17) & 127u], 1u);  // LDS atomic
        buckrec[pos] = rec;
    }
}

// ---- one wave per fine bucket: padded LDS bitmap -> unique count
__global__ void __launch_bounds__(256) pass_count(const u32* __restrict__ buckrec,
        const u32* __restrict__ hist2, u32* __restrict__ ucount, int n) {
    __shared__ u32 bm[BPB][WOPAD];
    u32 wave = threadIdx.x >> 6, lane = threadIdx.x & 63u;
    u32 bucket = blockIdx.x * BPB + wave;
    u32* B = bm[wave];
    #pragma unroll
    for (int j = 0; j < WPL; ++j) B[woidx(lane * WPL + j)] = 0u;
    __syncthreads();
    u32 start = hist2[bucket * S2];
    u32 end = (bucket + 1u < NBUCK) ? hist2[(bucket + 1u) * S2] : (u32)n;
    for (u32 i = start + lane; i < end; i += 64u) {
        u32 lk = (buckrec[i] >> 3) & LMASK;
        atomicOr(&B[woidx(lk >> 5)], 1u << (lk & 31u));
    }
    __syncthreads();
    u32 sum = 0;
    #pragma unroll
    for (int j = 0; j < WPL; ++j) sum += __popc(B[woidx(lane * WPL + j)]);
    u32 incl = sum;
    #pragma unroll
    for (int d = 1; d < 64; d <<= 1) {
        u32 t = __shfl_up(incl, d);
        if ((int)lane >= d) incl += t;
    }
    if (lane == 63u) ucount[bucket] = incl;
}

// ---- one wave per fine bucket: rank (group-prefix + popcount) + feats + emit
__global__ void __launch_bounds__(256) pass_emit(const u32* __restrict__ buckrec,
        const u32* __restrict__ hist2, const u32* __restrict__ ubase,
        const float* __restrict__ kern, float4* __restrict__ rows,
        float* __restrict__ feats, int n) {
    __shared__ u32 bm[BPB][WOPAD];
    __shared__ u32 wof8[BPB][64];         // per-lane-group (8-word) exclusive prefix
    __shared__ float fl[BPB][FCAP];
    u32 wave = threadIdx.x >> 6, lane = threadIdx.x & 63u;
    u32 bucket = blockIdx.x * BPB + wave;
    u32* B = bm[wave];
    float* F = fl[wave];
    #pragma unroll
    for (int j = 0; j < WPL; ++j) B[woidx(lane * WPL + j)] = 0u;
    for (u32 j = lane; j < FCAP; j += 64u) F[j] = 0.f;
    __syncthreads();
    u32 start = hist2[bucket * S2];
    u32 end = (bucket + 1u < NBUCK) ? hist2[(bucket + 1u) * S2] : (u32)n;
    for (u32 i = start + lane; i < end; i += 64u) {
        u32 lk = (buckrec[i] >> 3) & LMASK;
        atomicOr(&B[woidx(lk >> 5)], 1u << (lk & 31u));
    }
    __syncthreads();
    u32 pc[WPL]; u32 sum = 0;
    #pragma unroll
    for (int j = 0; j < WPL; ++j) { pc[j] = __popc(B[woidx(lane * WPL + j)]); sum += pc[j]; }
    u32 incl = sum;
    #pragma unroll
    for (int d = 1; d < 64; d <<= 1) {
        u32 t = __shfl_up(incl, d);
        if ((int)lane >= d) incl += t;
    }
    u32 lex = incl - sum;                 // lane-exclusive unique offset in bucket
    u32 uc = __shfl(incl, 63);            // bucket total uniques
    wof8[wave][lane] = lex;               // group prefix: lane owns words [lane*8,lane*8+8)
    __syncthreads();
    u32 base = ubase[bucket];
    bool lds_ok = (uc <= FCAP);
    if (!lds_ok) {                        // rare: zero own global window (feats not pre-filled)
        for (u32 j = lane; j < uc; j += 64u) feats[base + j] = 0.f;
    }
    __syncthreads();                      // uniform barrier: zero-stores drained before atomics
    for (u32 i = start + lane; i < end; i += 64u) {
        u32 rec = buckrec[i];
        u32 off = rec & 7u;
        float contrib = (float)(1u << off) * kern[off];
        u32 lk = (rec >> 3) & LMASK;
        u32 w = lk >> 5, bit = lk & 31u;
        u32 g = w >> 3;                   // owning lane-group
        u32 r = wof8[wave][g];
        for (u32 k = g * 8u; k < w; ++k) r += __popc(B[woidx(k)]);
        r += __popc(B[woidx(w)] & ((1u << bit) - 1u));
        if (lds_ok) atomicAdd(&F[r], contrib);
        else        atomicAdd(&feats[base + r], contrib);
    }
    __syncthreads();
    u32 rank = base + lex;
    u32 keyhi = bucket << LBITS;
    #pragma unroll
    for (int j = 0; j < WPL; ++j) {
        u32 bits = B[woidx(lane * WPL + j)];
        u32 kb = keyhi | ((lane * (u32)WPL + (u32)j) << 5);
        while (bits) {
            u32 t = __builtin_ctz(bits);
            bits &= bits - 1u;
            u32 key = kb | t;
            rows[rank++] = make_float4((float)(key >> 27), (float)(key & 511u),
                                       (float)((key >> 9) & 511u),
                                       (float)((key >> 18) & 511u));
        }
    }
    if (lds_ok) {
        for (u32 j = lane; j < uc; j += 64u) feats[base + j] = F[j];
    }
}

// pad rows AND feats in [U, n): feats is no longer globally pre-zeroed
__global__ void pad_fill(float4* __restrict__ rows, float* __restrict__ feats,
                         const u32* __restrict__ counter, int n) {
    int i = blockIdx.x * blockDim.x + threadIdx.x;
    if (i < n && (u32)i >= counter[0]) {
        rows[i] = make_float4(-1.f, -1.f, -1.f, -1.f);
        feats[i] = 0.f;
    }
}

extern "C" void kernel_launch(void* const* d_in, const int* in_sizes, int n_in,
                              void* d_out, int out_size, void* d_ws, size_t ws_size,
                              hipStream_t stream) {
    const int n = in_sizes[0] / 4;               // 4,000,000 points
    const int4* coords = (const int4*)d_in[0];
    const float* kern  = (const float*)d_in[1];
    const u32 NT = ((u32)n + TILE_A - 1) / TILE_A;        // 977 tiles
    const u32 G1 = 256 * NT;                               // histmat entries (250112)
    const u32 G2 = 256 * 128 * S2;                         // hist2 entries (262144)
    const u32 NB1 = (G1 + SCAN_ELEM - 1) / SCAN_ELEM;      // 123
    const u32 NB2 = (G2 + SCAN_ELEM - 1) / SCAN_ELEM;      // 128
    const u32 NB3 = (NBUCK + SCAN_ELEM - 1) / SCAN_ELEM;   // 16

    u32* wsp = (u32*)d_ws;
    u32* linrec  = wsp;                    // n  (reused as buckrec by part2b)
    u32* tmp     = linrec + n;             // n  (coarse-ordered records)
    u32* histmat = tmp + n;                // G1
    u32* hist2   = histmat + G1;           // G2
    u32* ucount  = hist2 + G2;             // NBUCK (scanned in place -> ubase)
    u32* counter = ucount + NBUCK;         // 4
    u32* spart   = counter + 4;            // 256
    u32* buckrec = linrec;

    float4* rows  = (float4*)d_out;                              // n rows
    float*  feats = (float*)((char*)d_out + (size_t)n * 16);     // n fp32

    phase_a<<<NT, 256, 0, stream>>>(coords, linrec, histmat, n, NT);
    scan_reduce<<<NB1, 256, 0, stream>>>(histmat, spart, G1);
    scan_small<<<1, 256, 0, stream>>>(spart, NB1, (u32*)nullptr);
    scan_apply<<<NB1, 256, 0, stream>>>(histmat, histmat, spart, G1);
    part1<<<NT, 256, 0, stream>>>(linrec, histmat, tmp, n, NT);
    part2a<<<256 * S2, 256, 0, stream>>>(tmp, histmat, hist2, n, NT);
    scan_reduce<<<NB2, 256, 0, stream>>>(hist2, spart, G2);
    scan_small<<<1, 256, 0, stream>>>(spart, NB2, (u32*)nullptr);
    scan_apply<<<NB2, 256, 0, stream>>>(hist2, hist2, spart, G2);
    part2b<<<256 * S2, 256, 0, stream>>>(tmp, histmat, hist2, buckrec, n, NT);
    pass_count<<<NBUCK / BPB, 256, 0, stream>>>(buckrec, hist2, ucount, n);
    scan_reduce<<<NB3, 256, 0, stream>>>(ucount, spart, NBUCK);
    scan_small<<<1, 256, 0, stream>>>(spart, NB3, counter);
    scan_apply<<<NB3, 256, 0, stream>>>(ucount, ucount, spart, NBUCK);
    pass_emit<<<NBUCK / BPB, 256, 0, stream>>>(buckrec, hist2, ucount, kern,
                                               rows, feats, n);
    pad_fill<<<((u32)n + 255) / 256, 256, 0, stream>>>(rows, feats, counter, n);
}